// Round 4
// baseline (115.095 us; speedup 1.0000x reference)
//
#include <hip/hip_runtime.h>
#include <math.h>

// Problem constants
#define B 2
#define N 8192            // points per batch (both preds and gts)
#define PTS_STRIDE (N*3)  // floats per batch
#define VOXEL 0.1f

#define TX 8              // x-points per thread (halves LDS reads per pair vs TX=4)
#define BLK 256           // threads per block (chamfer)
#define CHUNK 128         // y points per block
#define YSPLIT (N/CHUNK)  // 64
#define XTILES (N/(BLK*TX)) // 4
#define PBLK 1024

// ws layout (floats):
//  [0..15]    : gmin[arr][b][3]
//  [16]       : acc (float, partial-sum accumulator)
//  [17]       : ticket (uint)
//  [32 .. 32+65536)  : fallback per-point mins (rawmin[32768] then voxmin[32768])
//  [WS_PART ..)      : fast path partials: praw[slot][ys][x] then pvox (each 4*64*8192 floats)
#define WS_GMIN   0
#define WS_ACC    16
#define WS_TICKET 17
#define WS_MINS   32
#define MINS_TOTAL 65536
#define WS_PART   (WS_MINS + MINS_TOTAL)
#define PART_ONE  (4*YSPLIT*N)   // 2,097,152 floats
#define WS_NEEDED_FAST ((size_t)(WS_PART + 2*PART_ONE) * sizeof(float))  // ~17 MB

__device__ __forceinline__ float voxq(float v, float g) {
    return (float)(int)((v - g) / VOXEL);   // trunc like .astype(int32)
}

__global__ void __launch_bounds__(PBLK)
prep_kernel(const float* __restrict__ preds,
            const float* __restrict__ gts,
            float* __restrict__ ws) {
    const int arr = blockIdx.x >> 1;
    const int b   = blockIdx.x & 1;
    const float* base = (arr ? gts : preds) + b * PTS_STRIDE;

    float m0 = INFINITY, m1 = INFINITY, m2 = INFINITY;
    for (int i = threadIdx.x; i < N; i += PBLK) {
        float v0 = base[i*3+0], v1 = base[i*3+1], v2 = base[i*3+2];
        v0 = (v0 != v0) ? INFINITY : v0;   // NaN -> inf (matches masked_fill)
        v1 = (v1 != v1) ? INFINITY : v1;
        v2 = (v2 != v2) ? INFINITY : v2;
        m0 = fminf(m0, v0); m1 = fminf(m1, v1); m2 = fminf(m2, v2);
    }
    for (int off = 32; off; off >>= 1) {
        m0 = fminf(m0, __shfl_down(m0, off));
        m1 = fminf(m1, __shfl_down(m1, off));
        m2 = fminf(m2, __shfl_down(m2, off));
    }
    __shared__ float sm[16][3];
    const int wave = threadIdx.x >> 6, lane = threadIdx.x & 63;
    if (lane == 0) { sm[wave][0] = m0; sm[wave][1] = m1; sm[wave][2] = m2; }
    __syncthreads();
    if (threadIdx.x == 0) {
        float a0 = sm[0][0], a1 = sm[0][1], a2 = sm[0][2];
        for (int w = 1; w < 16; ++w) {
            a0 = fminf(a0, sm[w][0]);
            a1 = fminf(a1, sm[w][1]);
            a2 = fminf(a2, sm[w][2]);
        }
        const int gi = WS_GMIN + (arr*2 + b)*3;
        ws[gi+0] = a0; ws[gi+1] = a1; ws[gi+2] = a2;
        if (blockIdx.x == 0) {
            ws[WS_ACC] = 0.0f;
            ((unsigned int*)ws)[WS_TICKET] = 0u;
        }
    }
    // init fallback min arrays (each of the 4 blocks inits a quarter); cheap
    float* mins = ws + WS_MINS;
    const int quarter = MINS_TOTAL / 4;
    for (int i = threadIdx.x; i < quarter; i += PBLK)
        mins[blockIdx.x * quarter + i] = INFINITY;
}

// d(x,y) = (|y|^2 - 2 x.y) + |x|^2 ; min over y of first part, add |x|^2 after.
// fast=1: write per-(block,ys) partial mins with plain coalesced stores.
// fast=0: atomicMin-combine into the 65536-entry mins array.
__global__ void __launch_bounds__(BLK, 4)
chamfer_kernel(const float* __restrict__ preds,
               const float* __restrict__ gts,
               float* __restrict__ ws, int fast) {
    const int tid = threadIdx.x;
    const int dir = blockIdx.z & 1;      // 0: X=preds vs Y=gts ; 1: swapped
    const int b   = blockIdx.z >> 1;
    const int slot = blockIdx.z;
    const int arrX = dir, arrY = 1 - dir;
    const float* X = (dir ? gts : preds) + b * PTS_STRIDE;
    const float* Y = (dir ? preds : gts) + b * PTS_STRIDE;

    const float gx0 = ws[WS_GMIN + (arrX*2+b)*3+0];
    const float gx1 = ws[WS_GMIN + (arrX*2+b)*3+1];
    const float gx2 = ws[WS_GMIN + (arrX*2+b)*3+2];
    const float gy0 = ws[WS_GMIN + (arrY*2+b)*3+0];
    const float gy1 = ws[WS_GMIN + (arrY*2+b)*3+1];
    const float gy2 = ws[WS_GMIN + (arrY*2+b)*3+2];

    __shared__ float4 ldsR[CHUNK];
    __shared__ float4 ldsV[CHUNK];

    // stage one 128-point y chunk: raw (p, |p|^2) and vox (v, |v|^2)
    const int ys = blockIdx.y;
    if (tid < CHUNK) {
        const int yi = ys * CHUNK + tid;
        const float y0 = Y[yi*3+0], y1 = Y[yi*3+1], y2 = Y[yi*3+2];
        ldsR[tid] = make_float4(y0, y1, y2, fmaf(y0,y0, fmaf(y1,y1, y2*y2)));
        const float v0 = voxq(y0, gy0), v1 = voxq(y1, gy1), v2 = voxq(y2, gy2);
        ldsV[tid] = make_float4(v0, v1, v2, fmaf(v0,v0, fmaf(v1,v1, v2*v2)));
    }

    // x fragments (registers): a = -2x, |x|^2, for raw and vox
    const int x0 = blockIdx.x * (BLK * TX);
    float ar[TX][3], av[TX][3], xxr[TX], xxv[TX], mr[TX], mv[TX];
#pragma unroll
    for (int t = 0; t < TX; ++t) {
        const int xi = x0 + t*BLK + tid;
        const float p0 = X[xi*3+0], p1 = X[xi*3+1], p2 = X[xi*3+2];
        ar[t][0] = -2.0f*p0; ar[t][1] = -2.0f*p1; ar[t][2] = -2.0f*p2;
        xxr[t] = fmaf(p0,p0, fmaf(p1,p1, p2*p2));
        const float v0 = voxq(p0, gx0), v1 = voxq(p1, gx1), v2 = voxq(p2, gx2);
        av[t][0] = -2.0f*v0; av[t][1] = -2.0f*v1; av[t][2] = -2.0f*v2;
        xxv[t] = fmaf(v0,v0, fmaf(v1,v1, v2*v2));
        mr[t] = INFINITY; mv[t] = INFINITY;
    }
    __syncthreads();

#pragma unroll 4
    for (int j = 0; j < CHUNK; ++j) {
        const float4 yr = ldsR[j];
        const float4 yv = ldsV[j];
#pragma unroll
        for (int t = 0; t < TX; ++t) {
            const float dr = fmaf(ar[t][0], yr.x,
                             fmaf(ar[t][1], yr.y,
                             fmaf(ar[t][2], yr.z, yr.w)));
            mr[t] = fminf(mr[t], dr);
            const float dv = fmaf(av[t][0], yv.x,
                             fmaf(av[t][1], yv.y,
                             fmaf(av[t][2], yv.z, yv.w)));
            mv[t] = fminf(mv[t], dv);
        }
    }

    if (fast) {
        // plain coalesced stores: praw[slot][ys][x], pvox[slot][ys][x]
        float* praw = ws + WS_PART;
        float* pvox = praw + PART_ONE;
        const int rowbase = (slot*YSPLIT + ys)*N;
#pragma unroll
        for (int t = 0; t < TX; ++t) {
            const int xg = x0 + t*BLK + tid;
            praw[rowbase + xg] = mr[t] + xxr[t];
            pvox[rowbase + xg] = mv[t] + xxv[t];
        }
    } else {
        unsigned int* rawmin = (unsigned int*)(ws + WS_MINS);
        unsigned int* voxmin = rawmin + 32768;
#pragma unroll
        for (int t = 0; t < TX; ++t) {
            const int xg = x0 + t*BLK + tid;
            const int idx = slot * N + xg;
            atomicMin(&rawmin[idx], __float_as_uint(mr[t] + xxr[t]));
            atomicMin(&voxmin[idx], __float_as_uint(mv[t] + xxv[t]));
        }
    }
}

// 128 blocks x 256 threads = 32768 threads, one per (slot,x) pair.
// fast: min-reduce partials over ys, sum raw+vox, block-reduce, atomicAdd,
// ticketed last block writes out.
__global__ void __launch_bounds__(BLK)
finalize_kernel(float* __restrict__ ws, float* __restrict__ out, int fast) {
    const int g = blockIdx.x * BLK + threadIdx.x;   // 0..32767
    float s;
    if (fast) {
        const float* praw = ws + WS_PART;
        const float* pvox = praw + PART_ONE;
        const int slot = g >> 13;        // /8192
        const int xg   = g & (N-1);
        float m_r = INFINITY, m_v = INFINITY;
#pragma unroll 8
        for (int ys = 0; ys < YSPLIT; ++ys) {
            const int idx = (slot*YSPLIT + ys)*N + xg;
            m_r = fminf(m_r, praw[idx]);
            m_v = fminf(m_v, pvox[idx]);
        }
        s = m_r + m_v;
    } else {
        const float* mins = ws + WS_MINS;
        s = mins[g] + mins[32768 + g];
    }
    for (int off = 32; off; off >>= 1)
        s += __shfl_down(s, off);
    __shared__ float sm[4];
    const int wave = threadIdx.x >> 6, lane = threadIdx.x & 63;
    if (lane == 0) sm[wave] = s;
    __syncthreads();
    if (threadIdx.x == 0) {
        const float bs = sm[0] + sm[1] + sm[2] + sm[3];
        atomicAdd(ws + WS_ACC, bs);
        __threadfence();
        const unsigned int t = atomicAdd(&((unsigned int*)ws)[WS_TICKET], 1u);
        if (t == gridDim.x - 1) {
            __threadfence();
            const float total = atomicAdd(ws + WS_ACC, 0.0f);  // atomic read
            out[0] = total * (1.0f / 16384.0f);
        }
    }
}

extern "C" void kernel_launch(void* const* d_in, const int* in_sizes, int n_in,
                              void* d_out, int out_size, void* d_ws, size_t ws_size,
                              hipStream_t stream) {
    const float* preds = (const float*)d_in[0];
    const float* gts   = (const float*)d_in[1];
    float* ws  = (float*)d_ws;
    float* out = (float*)d_out;

    const int fast = (ws_size >= WS_NEEDED_FAST) ? 1 : 0;

    prep_kernel<<<dim3(4), dim3(PBLK), 0, stream>>>(preds, gts, ws);
    chamfer_kernel<<<dim3(XTILES, YSPLIT, 4), dim3(BLK), 0, stream>>>(preds, gts, ws, fast);
    finalize_kernel<<<dim3(32768/BLK), dim3(BLK), 0, stream>>>(ws, out, fast);
}